// Round 8
// baseline (332.751 us; speedup 1.0000x reference)
//
#include <hip/hip_runtime.h>
#include <hip/hip_bf16.h>
#include <math.h>

#define N_NODES 100000
#define N_EDGES 1600000
#define N_FEAT 64
#define HID 64
#define HL 256
#define N_GRAPHS 512

#define BUCKET_BITS 6
#define BUCKET_SIZE 64
#define NB ((N_NODES + BUCKET_SIZE - 1) / BUCKET_SIZE)   // 1563
#define LOFS_W (NB + 1)                                  // 1564
#define CAP 1792                   // per-bucket soff capacity incl. 8-pads
#define LREC_CAP 1792              // staged records per bucket (max ~1150)
#define EDGES_PER_BLOCK 2048
#define SCAT_BLOCKS ((N_EDGES + EDGES_PER_BLOCK - 1) / EDGES_PER_BLOCK)  // 782
#define F2B_BLOCKS (N_NODES * 16 / 256)                                  // 6250
#define WPREP_BLOCKS 128
#define ZOFF ((unsigned int)N_NODES * 128u)   // byte offset of the zero row
#define FUSE_BLOCKS ((N_NODES + 63) / 64)     // 1563

typedef short vbf8 __attribute__((ext_vector_type(8)));
typedef float vf4 __attribute__((ext_vector_type(4)));
typedef float vf2 __attribute__((ext_vector_type(2)));
typedef unsigned int vu4 __attribute__((ext_vector_type(4)));

// bf16 helpers (manual RNE; values are finite)
__device__ __forceinline__ unsigned short f2b(float f) {
    unsigned int u = __float_as_uint(f);
    return (unsigned short)((u + 0x7FFFu + ((u >> 16) & 1u)) >> 16);
}
__device__ __forceinline__ float b2f(unsigned short u) {
    return __uint_as_float(((unsigned int)u) << 16);
}
// packed fp32x2 -> bf16x2 (v_cvt_pk_bf16_f32, RNE — identical to f2b)
__device__ __forceinline__ unsigned pk2(float lo, float hi) {
    float2 f; f.x = lo; f.y = hi;
    __hip_bfloat162 h = __float22bfloat162_rn(f);
    unsigned r;
    __builtin_memcpy(&r, &h, 4);
    return r;
}
// bf16 pair -> float2 {lo, hi}
__device__ __forceinline__ vf2 bpair(unsigned int d) {
    vf2 r;
    r.x = __uint_as_float(d << 16);
    r.y = __uint_as_float(d & 0xFFFF0000u);
    return r;
}

// ---------------- mega prep: LDS bucket-sort + f2b + wprep -----------------
// Single-pass edge read: hist phase stages packed records + bucket ids in
// LDS (no 2nd global src/dst read); scatter phase is LDS-only. ebuf stream
// out via uint4. 64-node buckets (NB=1563). NO global atomics (round-5
// lesson: returned-value atomics at random addresses are latency-serial).

__global__ __launch_bounds__(256) void k_mega(
        const int* __restrict__ src, const int* __restrict__ dst,
        int* __restrict__ lofs, unsigned int* __restrict__ ebuf,
        const float4* __restrict__ x, uint2* __restrict__ xb,
        const float* __restrict__ wroot0, const float* __restrict__ wrel0,
        const float* __restrict__ wroot1, const float* __restrict__ wrel1,
        const float* __restrict__ wroot2, const float* __restrict__ wrel2,
        const float* __restrict__ wroot3, const float* __restrict__ wrel3,
        unsigned short* __restrict__ wt) {
    __shared__ int lh[NB];                               // 6.2 KB
    __shared__ int lsc[256];
    __shared__ unsigned short bkt[EDGES_PER_BLOCK];      // 4 KB
    __shared__ unsigned rstage[EDGES_PER_BLOCK];         // 8 KB
    __shared__ unsigned lrec[EDGES_PER_BLOCK];           // 8 KB
    int bid = blockIdx.x;
    int t = threadIdx.x;

    if (bid < SCAT_BLOCKS) {
        for (int i = t; i < NB; i += 256) lh[i] = 0;
        __syncthreads();
        int i0 = bid * EDGES_PER_BLOCK;
        int i1 = min(N_EDGES, i0 + EDGES_PER_BLOCK);
        int cnt = i1 - i0;
        // single pass: read src+dst once, stage rec+bucket, histogram
        for (int i = i0 + t; i < i1; i += 256) {
            int sN = src[i], d = dst[i];
            int b = d >> BUCKET_BITS;
            bkt[i - i0] = (unsigned short)b;
            rstage[i - i0] = ((unsigned)sN << 7) | (unsigned)(d & (BUCKET_SIZE - 1));
            atomicAdd(&lh[b], 1);
        }
        __syncthreads();
        // exclusive scan of lh[0..NB), 8 entries/thread
        int v[8];
        int s = 0;
        int base8 = t * 8;
#pragma unroll
        for (int j = 0; j < 8; j++) {
            v[j] = (base8 + j < NB) ? lh[base8 + j] : 0;
            s += v[j];
        }
        lsc[t] = s;
        __syncthreads();
        for (int off = 1; off < 256; off <<= 1) {
            int xx = lsc[t];
            int y = (t >= off) ? lsc[t - off] : 0;
            __syncthreads();
            lsc[t] = xx + y;
            __syncthreads();
        }
        int run = lsc[t] - s;   // exclusive prefix
        int* lrow = lofs + (size_t)bid * LOFS_W;
#pragma unroll
        for (int j = 0; j < 8; j++) {
            int b = base8 + j;
            if (b < NB) {
                lrow[b] = run;
                lh[b] = run;   // LDS cursor (each thread owns its 8 entries)
            }
            run += v[j];
        }
        if (t == 255) lrow[NB] = cnt;
        __syncthreads();
        // scatter within LDS (no global reads)
        for (int j = t; j < cnt; j += 256) {
            int b = bkt[j];
            unsigned rec = rstage[j];
            int p = atomicAdd(&lh[b], 1);
            lrec[p] = rec;
        }
        __syncthreads();
        // stream out coalesced, 16B per thread (cnt is a multiple of 4)
        unsigned* eb = ebuf + (size_t)bid * EDGES_PER_BLOCK;
        for (int j = 4 * t; j < cnt; j += 1024) {
            vu4 q = *(const vu4*)&lrec[j];
            *(vu4*)&eb[j] = q;
        }
    } else if (bid < SCAT_BLOCKS + F2B_BLOCKS) {
        // ---- fp32 -> bf16 convert (packed cvt) ----
        int i = (bid - SCAT_BLOCKS) * 256 + t;
        if (i < N_NODES * 16) {
            float4 v = x[i];
            uint2 o;
            o.x = pk2(v.x, v.y);
            o.y = pk2(v.z, v.w);
            xb[i] = o;
        }
    } else {
        // ---- weight prep: Wt[layer][n][k], k = [wroot|wrel] ----
        int gi = (bid - SCAT_BLOCKS - F2B_BLOCKS) * 256 + t;
        if (gi < 4 * 64 * 128) {
            int layer = gi >> 13;
            int i = gi & 8191;
            int nn = i >> 7, k = i & 127;
            const float* wr = (layer == 0) ? wroot0 : (layer == 1) ? wroot1
                             : (layer == 2) ? wroot2 : wroot3;
            const float* wl = (layer == 0) ? wrel0 : (layer == 1) ? wrel1
                             : (layer == 2) ? wrel2 : wrel3;
            float v = (k < 64) ? wr[k * 64 + nn] : wl[(k - 64) * 64 + nn];
            wt[gi] = f2b(v);
        }
    }
}

// ---------------- per-bucket: gather runs -> hist -> padded scan -> soff ---
// 64-node buckets: 1563 blocks (2x block parallelism, halved serial depth).

__global__ __launch_bounds__(256) void k_fscatter2(
        const unsigned int* __restrict__ ebuf, const int* __restrict__ lofs,
        int2* __restrict__ re, unsigned int* __restrict__ soff,
        unsigned short* __restrict__ hbA, unsigned short* __restrict__ hbB, int n) {
    __shared__ int rcnt[1024];
    __shared__ int rbase[1024];
    __shared__ int rpre[1024];
    __shared__ int tsc[256];
    __shared__ unsigned lrec[LREC_CAP];
    __shared__ int lcnt[BUCKET_SIZE];
    __shared__ int sc[BUCKET_SIZE];
    __shared__ int cur[BUCKET_SIZE];
    int b = blockIdx.x;
    int n0 = b * BUCKET_SIZE;
    int t = threadIdx.x;
    if (b == 0 && t < 16) {
        // zero the pad rows (128 B each) of both h buffers
        uint4 z = make_uint4(0u, 0u, 0u, 0u);
        unsigned short* hp = (t < 8) ? hbA : hbB;
        ((uint4*)(hp + (size_t)N_NODES * 64))[t & 7] = z;
    }
    // load per-block run counts/bases for this bucket
    for (int blk = t; blk < 1024; blk += 256) {
        int c = 0, ba = 0;
        if (blk < SCAT_BLOCKS) {
            const int* lr = lofs + (size_t)blk * LOFS_W + b;
            ba = lr[0];
            c = lr[1] - ba;
        }
        rcnt[blk] = c;
        rbase[blk] = ba;
    }
    __syncthreads();
    // scan 1024 run counts (4 per thread)
    int c0 = rcnt[4 * t], c1 = rcnt[4 * t + 1], c2 = rcnt[4 * t + 2], c3 = rcnt[4 * t + 3];
    int s4 = c0 + c1 + c2 + c3;
    tsc[t] = s4;
    __syncthreads();
    for (int off = 1; off < 256; off <<= 1) {
        int xx = tsc[t];
        int y = (t >= off) ? tsc[t - off] : 0;
        __syncthreads();
        tsc[t] = xx + y;
        __syncthreads();
    }
    int ex = tsc[t] - s4;
    rpre[4 * t] = ex;
    rpre[4 * t + 1] = ex + c0;
    rpre[4 * t + 2] = ex + c0 + c1;
    rpre[4 * t + 3] = ex + c0 + c1 + c2;
    __syncthreads();
    int cb = tsc[255];   // total records in this bucket
    // gather runs into LDS
    for (int blk = t; blk < SCAT_BLOCKS; blk += 256) {
        int c = rcnt[blk];
        int dsto = rpre[blk];
        const unsigned* sp = ebuf + (size_t)blk * EDGES_PER_BLOCK + rbase[blk];
        for (int j = 0; j < c; j++) lrec[dsto + j] = sp[j];
    }
    if (t < BUCKET_SIZE) lcnt[t] = 0;
    __syncthreads();
    // per-node histogram
    for (int r = t; r < cb; r += 256)
        atomicAdd(&lcnt[lrec[r] & (BUCKET_SIZE - 1)], 1);
    __syncthreads();
    int v = 0, pcnt = 0;
    if (t < BUCKET_SIZE) {
        v = lcnt[t];
        pcnt = (v + 7) & ~7;     // pad to multiple of 8
        sc[t] = pcnt;
    }
    __syncthreads();
    for (int off = 1; off < BUCKET_SIZE; off <<= 1) {
        int xx = 0;
        if (t < BUCKET_SIZE) {
            xx = sc[t];
            if (t >= off) xx += sc[t - off];
        }
        __syncthreads();
        if (t < BUCKET_SIZE) sc[t] = xx;
        __syncthreads();
    }
    if (t < BUCKET_SIZE) {
        int start = b * CAP + sc[t] - pcnt;   // exclusive scan of padded counts
        if (n0 + t < n) re[n0 + t] = make_int2(start, start + v);
        cur[t] = start;
        for (int z = start + v; z < start + pcnt; z++) soff[z] = ZOFF;
    }
    __syncthreads();
    for (int r = t; r < cb; r += 256) {
        unsigned rec = lrec[r];
        int p = atomicAdd(&cur[rec & (BUCKET_SIZE - 1)], 1);
        soff[p] = rec & ~127u;   // src * 128 byte offset
    }
}

// ---------------- fused layer: agg (LDS) + MFMA gemm -----------------------
// Phase 1 (8 waves x 8 nodes): aggb row for each of the block's 64 nodes is
// accumulated in registers (8-lane groups, 16B slice per lane, per-group
// divergent loop over its own pad-4 edge count; pads are ZOFF -> zero row)
// and stored to LDS (XOR-swizzled 16B chunks). Phase 2 (waves 0-3): the
// MFMA gemm reads A-fragments afr[0/1] from global hb, afr[2/3] from LDS.
// k_layer is at its byte-path floor (r7): random 128B gathers over 12.8MB,
// ~86MB L2-miss at ~2TB/s; gather structure and store flavor don't move it.

template <int RELU>
__global__ __launch_bounds__(512) void k_layer(
    const unsigned short* __restrict__ hb,
    const unsigned short* __restrict__ wt, const float* __restrict__ brel,
    unsigned short* __restrict__ hbout,
    const int2* __restrict__ re, const unsigned int* __restrict__ soff, int n) {
    __shared__ float scx[4][16 * 68];
    __shared__ unsigned int agg_lds[64][32];   // 64 rows x 128B, swizzled

    int tid = threadIdx.x;
    int w = tid >> 6, l = tid & 63;
    int r0 = blockIdx.x * 64;

    // ---------- phase 1: aggregate the block's 64 rows into LDS ----------
    {
        int g = l >> 3;            // sub-node in wave (0..7)
        int sl = l & 7;            // 16B feature slice (0..7)
        int nl = w * 8 + g;        // node_local (0..63)
        int i = r0 + nl;
        int ii = min(i, n - 1);
        int2 bd = re[ii];
        int e0 = bd.x;
        int cnt = (i < n) ? (bd.y - bd.x) : 0;
        int pc4 = (cnt + 3) & ~3;  // pad-4 (<= stored pad-8 region, ZOFF fill)
        const char* base = (const char*)hb + sl * 16;

        vf2 A[4], B[4];
#pragma unroll
        for (int f = 0; f < 4; f++) { A[f] = (vf2){0.f, 0.f}; B[f] = (vf2){0.f, 0.f}; }

        // e0 is a multiple of 8 -> soff + e0 + it is 16B-aligned
        for (int it = 0; it < pc4; it += 4) {
            vu4 ov = *(const vu4*)(soff + e0 + it);
            uint4 d0 = *(const uint4*)(base + ov.x);
            uint4 d1 = *(const uint4*)(base + ov.y);
            uint4 d2 = *(const uint4*)(base + ov.z);
            uint4 d3 = *(const uint4*)(base + ov.w);
            A[0] += bpair(d0.x); A[1] += bpair(d0.y);
            A[2] += bpair(d0.z); A[3] += bpair(d0.w);
            B[0] += bpair(d1.x); B[1] += bpair(d1.y);
            B[2] += bpair(d1.z); B[3] += bpair(d1.w);
            A[0] += bpair(d2.x); A[1] += bpair(d2.y);
            A[2] += bpair(d2.z); A[3] += bpair(d2.w);
            B[0] += bpair(d3.x); B[1] += bpair(d3.y);
            B[2] += bpair(d3.z); B[3] += bpair(d3.w);
        }

        vf2 s0 = A[0] + B[0];
        vf2 s1 = A[1] + B[1];
        vf2 s2 = A[2] + B[2];
        vf2 s3 = A[3] + B[3];
        uint4 o;
        o.x = pk2(s0.x, s0.y);
        o.y = pk2(s1.x, s1.y);
        o.z = pk2(s2.x, s2.y);
        o.w = pk2(s3.x, s3.y);
        int c16 = sl ^ (nl & 7);   // XOR swizzle of 16B chunks within the row
        *(uint4*)&agg_lds[nl][c16 * 4] = o;
    }
    __syncthreads();

    // ---------- phase 2: MFMA gemm (waves 0-3) ----------
    if (w < 4) {
        int lm = l & 15, q = l >> 4;
        int row = w * 16 + lm;
        int arow = r0 + row;
        if (arow >= n) arow = n - 1;
        const unsigned short* ah = hb + (size_t)arow * 64 + q * 8;
        vbf8 afr[4];
        afr[0] = *(const vbf8*)(ah);
        afr[1] = *(const vbf8*)(ah + 32);
        afr[2] = *(const vbf8*)&agg_lds[row][((q) ^ (lm & 7)) * 4];
        afr[3] = *(const vbf8*)&agg_lds[row][((q + 4) ^ (lm & 7)) * 4];

        vf4 acc[4];
#pragma unroll
        for (int t = 0; t < 4; t++) acc[t] = (vf4){0.f, 0.f, 0.f, 0.f};

#pragma unroll
        for (int t = 0; t < 4; t++) {
            const unsigned short* wrow = wt + (size_t)(t * 16 + lm) * 128 + q * 8;
#pragma unroll
            for (int s = 0; s < 4; s++) {
                vbf8 bfr = *(const vbf8*)(wrow + s * 32);
                acc[t] = __builtin_amdgcn_mfma_f32_16x16x32_bf16(afr[s], bfr, acc[t], 0, 0, 0);
            }
        }

        float* sw_ = scx[w];
#pragma unroll
        for (int t = 0; t < 4; t++) {
            float b = brel[t * 16 + lm];
#pragma unroll
            for (int i = 0; i < 4; i++) {
                float v = acc[t][i] + b;
                if (RELU) v = fmaxf(v, 0.f);
                sw_[(q * 4 + i) * 68 + t * 16 + lm] = v;
            }
        }
        int rr = l >> 2, cs = l & 3;
        int node = r0 + w * 16 + rr;
        if (node < n) {
            const float* rp = sw_ + rr * 68 + cs * 16;
            float4 v0 = *(const float4*)(rp);
            float4 v1 = *(const float4*)(rp + 4);
            float4 v2 = *(const float4*)(rp + 8);
            float4 v3 = *(const float4*)(rp + 12);
            vu4 o0, o1;
            o0.x = pk2(v0.x, v0.y);
            o0.y = pk2(v0.z, v0.w);
            o0.z = pk2(v1.x, v1.y);
            o0.w = pk2(v1.z, v1.w);
            o1.x = pk2(v2.x, v2.y);
            o1.y = pk2(v2.z, v2.w);
            o1.z = pk2(v3.x, v3.y);
            o1.w = pk2(v3.z, v3.w);
            vu4* op = (vu4*)(hbout + (size_t)node * 64 + cs * 16);
            op[0] = o0;
            op[1] = o1;
        }
    }
}

// ---------------- fused pool + MLP head (one block per graph) --------------

__global__ __launch_bounds__(256) void k_poolmlp(
    const unsigned short* __restrict__ hb, const int* __restrict__ batch,
    const float* __restrict__ T, const float* __restrict__ w1,
    const float* __restrict__ b1, const float* __restrict__ w2,
    const float* __restrict__ b2, const float* __restrict__ w3,
    const float* __restrict__ b3, float* __restrict__ out, int n) {
    __shared__ float psum[4][64];
    __shared__ float pmax[4][64];
    __shared__ float sin_[200];
    __shared__ float so1[256];
    __shared__ float red[256];
    int g = blockIdx.x, t = threadIdx.x;
    int l = t & 63, c = t >> 6;

    // bounds via binary search (batch sorted)
    int lo = 0, hi = n;
    while (lo < hi) { int m = (lo + hi) >> 1; if (batch[m] < g) lo = m + 1; else hi = m; }
    int s0 = lo;
    int lo2 = s0, hi2 = n;
    while (lo2 < hi2) { int m = (lo2 + hi2) >> 1; if (batch[m] < g + 1) lo2 = m + 1; else hi2 = m; }
    int s1 = lo2;

    // pooling: unroll x4 (independent loads in flight)
    float sa0 = 0.f, sa1 = 0.f, sa2 = 0.f, sa3 = 0.f;
    float ma0 = -INFINITY, ma1 = -INFINITY, ma2 = -INFINITY, ma3 = -INFINITY;
    int nn = s0 + c;
    for (; nn + 12 < s1; nn += 16) {
        float v0 = b2f(hb[(size_t)nn * 64 + l]);
        float v1 = b2f(hb[(size_t)(nn + 4) * 64 + l]);
        float v2 = b2f(hb[(size_t)(nn + 8) * 64 + l]);
        float v3 = b2f(hb[(size_t)(nn + 12) * 64 + l]);
        sa0 += v0; sa1 += v1; sa2 += v2; sa3 += v3;
        ma0 = fmaxf(ma0, v0); ma1 = fmaxf(ma1, v1);
        ma2 = fmaxf(ma2, v2); ma3 = fmaxf(ma3, v3);
    }
    for (; nn < s1; nn += 4) {
        float v = b2f(hb[(size_t)nn * 64 + l]);
        sa0 += v;
        ma0 = fmaxf(ma0, v);
    }
    psum[c][l] = (sa0 + sa1) + (sa2 + sa3);
    pmax[c][l] = fmaxf(fmaxf(ma0, ma1), fmaxf(ma2, ma3));
    __syncthreads();
    if (t < 64) {
        float s = (psum[0][t] + psum[1][t]) + (psum[2][t] + psum[3][t]);
        float mx = fmaxf(fmaxf(pmax[0][t], pmax[1][t]), fmaxf(pmax[2][t], pmax[3][t]));
        int cnt = s1 - s0;
        float mean = s / fmaxf((float)cnt, 1.f);
        if (cnt == 0) mx = 0.f;
        sin_[t] = mx;
        sin_[64 + t] = mean;
        sin_[128 + t] = s;
        if (t == 0) {
            sin_[192] = T[g];
#pragma unroll
            for (int z = 193; z < 200; z++) sin_[z] = 0.f;  // pad for x8 batch
        }
    }
    __syncthreads();

    // layer 1: 193-K matvec, batched x8 (pad zeros make 200 safe)
    float a = b1[t];
    {
        float wv[8];
        for (int k = 0; k < 192; k += 8) {
#pragma unroll
            for (int u = 0; u < 8; u++) wv[u] = w1[(k + u) * 256 + t];
#pragma unroll
            for (int u = 0; u < 8; u++) a += sin_[k + u] * wv[u];
        }
        a += sin_[192] * w1[192 * 256 + t];
    }
    a = fmaxf(a, 0.f);
    so1[t] = a;
    __syncthreads();

    // layer 2: 256-K matvec, batched x8
    float a2 = b2[t];
    {
        float wv[8];
        for (int k = 0; k < 256; k += 8) {
#pragma unroll
            for (int u = 0; u < 8; u++) wv[u] = w2[(k + u) * 256 + t];
#pragma unroll
            for (int u = 0; u < 8; u++) a2 += so1[k + u] * wv[u];
        }
    }
    a2 = fmaxf(a2, 0.f);
    red[t] = a2 * w3[t];
    __syncthreads();
    for (int s = 128; s > 0; s >>= 1) {
        if (t < s) red[t] += red[t + s];
        __syncthreads();
    }
    if (t == 0) out[g] = red[0] + b3[0];
}

extern "C" void kernel_launch(void* const* d_in, const int* in_sizes, int n_in,
                              void* d_out, int out_size, void* d_ws, size_t ws_size,
                              hipStream_t stream) {
    const int N = N_NODES, E = N_EDGES, G = N_GRAPHS;

    const float* x = (const float*)d_in[0];
    const int* ei = (const int*)d_in[1];
    const int* batch = (const int*)d_in[2];
    const float* T = (const float*)d_in[3];
    const float* wrel[4] = {(const float*)d_in[4], (const float*)d_in[7],
                            (const float*)d_in[10], (const float*)d_in[13]};
    const float* brel[4] = {(const float*)d_in[5], (const float*)d_in[8],
                            (const float*)d_in[11], (const float*)d_in[14]};
    const float* wroot[4] = {(const float*)d_in[6], (const float*)d_in[9],
                             (const float*)d_in[12], (const float*)d_in[15]};
    const float* w1 = (const float*)d_in[16];
    const float* b1 = (const float*)d_in[17];
    const float* w2 = (const float*)d_in[18];
    const float* b2 = (const float*)d_in[19];
    const float* w3 = (const float*)d_in[20];
    const float* b3 = (const float*)d_in[21];
    float* out = (float*)d_out;

    const int* esrc = ei;
    const int* edst = ei + E;

    // workspace layout (~50 MB)
    char* ws = (char*)d_ws;
    size_t off = 0;
    auto alloc = [&](size_t bytes) {
        size_t r = off;
        off = (off + bytes + 255) & ~(size_t)255;
        return r;
    };
    int* lofs = (int*)(ws + alloc((size_t)SCAT_BLOCKS * LOFS_W * 4));
    int2* re = (int2*)(ws + alloc((size_t)N * 8));
    unsigned int* soff = (unsigned int*)(ws + alloc((size_t)NB * CAP * 4));
    unsigned int* ebuf = (unsigned int*)(ws + alloc((size_t)SCAT_BLOCKS * EDGES_PER_BLOCK * 4));
    unsigned short* hbA = (unsigned short*)(ws + alloc((size_t)N * 64 * 2 + 128));
    unsigned short* hbB = (unsigned short*)(ws + alloc((size_t)N * 64 * 2 + 128));
    unsigned short* wt = (unsigned short*)(ws + alloc((size_t)4 * 64 * 128 * 2));

    // 1. prep: mega (LDS bucket-sort scatter + f2b + wprep), then fscatter2
    k_mega<<<SCAT_BLOCKS + F2B_BLOCKS + WPREP_BLOCKS, 256, 0, stream>>>(
        esrc, edst, lofs, ebuf, (const float4*)x, (uint2*)hbA,
        wroot[0], wrel[0], wroot[1], wrel[1],
        wroot[2], wrel[2], wroot[3], wrel[3], wt);
    k_fscatter2<<<NB, 256, 0, stream>>>(ebuf, lofs, re, soff, hbA, hbB, N);

    // 2. four fused conv layers (agg in LDS + MFMA gemm, bf16 ping-pong)
    k_layer<1><<<FUSE_BLOCKS, 512, 0, stream>>>(hbA, wt + 0 * 8192, brel[0], hbB, re, soff, N);
    k_layer<1><<<FUSE_BLOCKS, 512, 0, stream>>>(hbB, wt + 1 * 8192, brel[1], hbA, re, soff, N);
    k_layer<1><<<FUSE_BLOCKS, 512, 0, stream>>>(hbA, wt + 2 * 8192, brel[2], hbB, re, soff, N);
    k_layer<0><<<FUSE_BLOCKS, 512, 0, stream>>>(hbB, wt + 3 * 8192, brel[3], hbA, re, soff, N);

    // 3. fused pooling + MLP head
    k_poolmlp<<<G, 256, 0, stream>>>(hbA, batch, T, w1, b1, w2, b2, w3, b3, out, N);
}

// Round 9
// 330.303 us; speedup vs baseline: 1.0074x; 1.0074x over previous
//
#include <hip/hip_runtime.h>
#include <hip/hip_bf16.h>
#include <math.h>

#define N_NODES 100000
#define N_EDGES 1600000
#define N_FEAT 64
#define HID 64
#define HL 256
#define N_GRAPHS 512

#define BUCKET_BITS 7
#define BUCKET_SIZE 128
#define NB ((N_NODES + BUCKET_SIZE - 1) / BUCKET_SIZE)   // 782
#define LOFS_W (NB + 1)                                  // 783
#define CAP 3584                   // per-bucket soff capacity incl. 8-pads
#define LREC_CAP 3584              // staged records per bucket (max ~2300)
#define EDGES_PER_BLOCK 2048
#define SCAT_BLOCKS ((N_EDGES + EDGES_PER_BLOCK - 1) / EDGES_PER_BLOCK)  // 782
#define F2B_BLOCKS (N_NODES * 16 / 256)                                  // 6250
#define WPREP_BLOCKS 128
#define ZOFF ((unsigned int)N_NODES * 128u)   // byte offset of the zero row
#define FUSE_BLOCKS ((N_NODES + 63) / 64)     // 1563

typedef short vbf8 __attribute__((ext_vector_type(8)));
typedef float vf4 __attribute__((ext_vector_type(4)));
typedef float vf2 __attribute__((ext_vector_type(2)));
typedef unsigned int vu4 __attribute__((ext_vector_type(4)));

// bf16 helpers (manual RNE; values are finite)
__device__ __forceinline__ unsigned short f2b(float f) {
    unsigned int u = __float_as_uint(f);
    return (unsigned short)((u + 0x7FFFu + ((u >> 16) & 1u)) >> 16);
}
__device__ __forceinline__ float b2f(unsigned short u) {
    return __uint_as_float(((unsigned int)u) << 16);
}
// packed fp32x2 -> bf16x2 (v_cvt_pk_bf16_f32, RNE — identical to f2b)
__device__ __forceinline__ unsigned pk2(float lo, float hi) {
    float2 f; f.x = lo; f.y = hi;
    __hip_bfloat162 h = __float22bfloat162_rn(f);
    unsigned r;
    __builtin_memcpy(&r, &h, 4);
    return r;
}
// bf16 pair -> float2 {lo, hi}
__device__ __forceinline__ vf2 bpair(unsigned int d) {
    vf2 r;
    r.x = __uint_as_float(d << 16);
    r.y = __uint_as_float(d & 0xFFFF0000u);
    return r;
}

// ---------------- mega prep: LDS bucket-sort + f2b + wprep -----------------
// EPB=2048: 782 scatter blocks (3/CU). Row-major lofs (r6 transpose neutral).
// Double-pass edge read (r8 single-pass was neutral/worse). NO global
// atomics (r5 lesson: returned-value atomics at random addresses are
// latency-serial + 64B-line write-amplified).

__global__ __launch_bounds__(256) void k_mega(
        const int* __restrict__ src, const int* __restrict__ dst,
        int* __restrict__ lofs, unsigned int* __restrict__ ebuf,
        const float4* __restrict__ x, uint2* __restrict__ xb,
        const float* __restrict__ wroot0, const float* __restrict__ wrel0,
        const float* __restrict__ wroot1, const float* __restrict__ wrel1,
        const float* __restrict__ wroot2, const float* __restrict__ wrel2,
        const float* __restrict__ wroot3, const float* __restrict__ wrel3,
        unsigned short* __restrict__ wt) {
    __shared__ int lh[NB];
    __shared__ int lsc[256];
    __shared__ unsigned lrec[EDGES_PER_BLOCK];
    int bid = blockIdx.x;
    int t = threadIdx.x;

    if (bid < SCAT_BLOCKS) {
        for (int i = t; i < NB; i += 256) lh[i] = 0;
        __syncthreads();
        int i0 = bid * EDGES_PER_BLOCK;
        int i1 = min(N_EDGES, i0 + EDGES_PER_BLOCK);
        int cnt = i1 - i0;
        for (int i = i0 + t; i < i1; i += 256)
            atomicAdd(&lh[dst[i] >> BUCKET_BITS], 1);
        __syncthreads();
        // exclusive scan of lh[0..NB), 4 entries/thread
        int v[4];
        int s = 0;
        int base4 = t * 4;
#pragma unroll
        for (int j = 0; j < 4; j++) {
            v[j] = (base4 + j < NB) ? lh[base4 + j] : 0;
            s += v[j];
        }
        lsc[t] = s;
        __syncthreads();
        for (int off = 1; off < 256; off <<= 1) {
            int xx = lsc[t];
            int y = (t >= off) ? lsc[t - off] : 0;
            __syncthreads();
            lsc[t] = xx + y;
            __syncthreads();
        }
        int run = lsc[t] - s;   // exclusive prefix
        int* lrow = lofs + (size_t)bid * LOFS_W;
#pragma unroll
        for (int j = 0; j < 4; j++) {
            int b = base4 + j;
            if (b < NB) {
                lrow[b] = run;
                lh[b] = run;   // LDS cursor (all lh reads completed pre-scan)
            }
            run += v[j];
        }
        if (t == 255) lrow[NB] = cnt;
        __syncthreads();
        // scatter into LDS
        for (int i = i0 + t; i < i1; i += 256) {
            int sN = src[i], d = dst[i];
            int b = d >> BUCKET_BITS;
            int p = atomicAdd(&lh[b], 1);
            lrec[p] = ((unsigned)sN << 7) | (unsigned)(d & 127);
        }
        __syncthreads();
        // stream out coalesced
        unsigned* eb = ebuf + (size_t)bid * EDGES_PER_BLOCK;
        for (int j = t; j < cnt; j += 256) eb[j] = lrec[j];
    } else if (bid < SCAT_BLOCKS + F2B_BLOCKS) {
        // ---- fp32 -> bf16 convert (packed cvt) ----
        int i = (bid - SCAT_BLOCKS) * 256 + t;
        if (i < N_NODES * 16) {
            float4 v = x[i];
            uint2 o;
            o.x = pk2(v.x, v.y);
            o.y = pk2(v.z, v.w);
            xb[i] = o;
        }
    } else {
        // ---- weight prep: Wt[layer][n][k], k = [wroot|wrel] ----
        int gi = (bid - SCAT_BLOCKS - F2B_BLOCKS) * 256 + t;
        if (gi < 4 * 64 * 128) {
            int layer = gi >> 13;
            int i = gi & 8191;
            int nn = i >> 7, k = i & 127;
            const float* wr = (layer == 0) ? wroot0 : (layer == 1) ? wroot1
                             : (layer == 2) ? wroot2 : wroot3;
            const float* wl = (layer == 0) ? wrel0 : (layer == 1) ? wrel1
                             : (layer == 2) ? wrel2 : wrel3;
            float v = (k < 64) ? wr[k * 64 + nn] : wl[(k - 64) * 64 + nn];
            wt[gi] = f2b(v);
        }
    }
}

// ---------------- per-bucket: gather runs -> hist -> padded scan -> soff ---

__global__ __launch_bounds__(256) void k_fscatter2(
        const unsigned int* __restrict__ ebuf, const int* __restrict__ lofs,
        int2* __restrict__ re, unsigned int* __restrict__ soff,
        unsigned short* __restrict__ hbA, unsigned short* __restrict__ hbB, int n) {
    __shared__ int rcnt[1024];
    __shared__ int rbase[1024];
    __shared__ int rpre[1024];
    __shared__ int tsc[256];
    __shared__ unsigned lrec[LREC_CAP];
    __shared__ int lcnt[BUCKET_SIZE];
    __shared__ int sc[BUCKET_SIZE];
    __shared__ int cur[BUCKET_SIZE];
    int b = blockIdx.x;
    int n0 = b * BUCKET_SIZE;
    int t = threadIdx.x;
    if (b == 0 && t < 16) {
        // zero the pad rows (128 B each) of both h buffers
        uint4 z = make_uint4(0u, 0u, 0u, 0u);
        unsigned short* hp = (t < 8) ? hbA : hbB;
        ((uint4*)(hp + (size_t)N_NODES * 64))[t & 7] = z;
    }
    // load per-block run counts/bases for this bucket
    for (int blk = t; blk < 1024; blk += 256) {
        int c = 0, ba = 0;
        if (blk < SCAT_BLOCKS) {
            const int* lr = lofs + (size_t)blk * LOFS_W + b;
            ba = lr[0];
            c = lr[1] - ba;
        }
        rcnt[blk] = c;
        rbase[blk] = ba;
    }
    __syncthreads();
    // scan 1024 run counts (4 per thread)
    int c0 = rcnt[4 * t], c1 = rcnt[4 * t + 1], c2 = rcnt[4 * t + 2], c3 = rcnt[4 * t + 3];
    int s4 = c0 + c1 + c2 + c3;
    tsc[t] = s4;
    __syncthreads();
    for (int off = 1; off < 256; off <<= 1) {
        int xx = tsc[t];
        int y = (t >= off) ? tsc[t - off] : 0;
        __syncthreads();
        tsc[t] = xx + y;
        __syncthreads();
    }
    int ex = tsc[t] - s4;
    rpre[4 * t] = ex;
    rpre[4 * t + 1] = ex + c0;
    rpre[4 * t + 2] = ex + c0 + c1;
    rpre[4 * t + 3] = ex + c0 + c1 + c2;
    __syncthreads();
    int cb = tsc[255];   // total records in this bucket
    // gather runs into LDS
    for (int blk = t; blk < SCAT_BLOCKS; blk += 256) {
        int c = rcnt[blk];
        int dsto = rpre[blk];
        const unsigned* sp = ebuf + (size_t)blk * EDGES_PER_BLOCK + rbase[blk];
        for (int j = 0; j < c; j++) lrec[dsto + j] = sp[j];
    }
    if (t < BUCKET_SIZE) lcnt[t] = 0;
    __syncthreads();
    // per-node histogram
    for (int r = t; r < cb; r += 256)
        atomicAdd(&lcnt[lrec[r] & 127u], 1);
    __syncthreads();
    int v = 0, pcnt = 0;
    if (t < BUCKET_SIZE) {
        v = lcnt[t];
        pcnt = (v + 7) & ~7;     // pad to multiple of 8
        sc[t] = pcnt;
    }
    __syncthreads();
    for (int off = 1; off < BUCKET_SIZE; off <<= 1) {
        int xx = 0;
        if (t < BUCKET_SIZE) {
            xx = sc[t];
            if (t >= off) xx += sc[t - off];
        }
        __syncthreads();
        if (t < BUCKET_SIZE) sc[t] = xx;
        __syncthreads();
    }
    if (t < BUCKET_SIZE) {
        int start = b * CAP + sc[t] - pcnt;   // exclusive scan of padded counts
        if (n0 + t < n) re[n0 + t] = make_int2(start, start + v);
        cur[t] = start;
        for (int z = start + v; z < start + pcnt; z++) soff[z] = ZOFF;
    }
    __syncthreads();
    for (int r = t; r < cb; r += 256) {
        unsigned rec = lrec[r];
        int p = atomicAdd(&cur[rec & 127u], 1);
        soff[p] = rec & ~127u;   // src * 128 byte offset
    }
}

// ---------------- fused layer: agg (LDS) + MFMA gemm -----------------------
// Phase 1 (8 waves x 8 nodes): aggb row for each of the block's 64 nodes is
// accumulated in registers (8-lane groups, 16B slice per lane, per-group
// divergent loop over its own pad-4 edge count; pads are ZOFF -> zero row)
// and stored to LDS (XOR-swizzled 16B chunks). Phase 2 (waves 0-3): the
// MFMA gemm reads A-fragments afr[0/1] from global hb, afr[2/3] from LDS.
// k_layer is at its byte-path floor (r7): random 128B gathers over 12.8MB,
// ~86MB L2-miss at ~2.35TB/s; gather structure and store flavor don't move it.

template <int RELU>
__global__ __launch_bounds__(512) void k_layer(
    const unsigned short* __restrict__ hb,
    const unsigned short* __restrict__ wt, const float* __restrict__ brel,
    unsigned short* __restrict__ hbout,
    const int2* __restrict__ re, const unsigned int* __restrict__ soff, int n) {
    __shared__ float scx[4][16 * 68];
    __shared__ unsigned int agg_lds[64][32];   // 64 rows x 128B, swizzled

    int tid = threadIdx.x;
    int w = tid >> 6, l = tid & 63;
    int r0 = blockIdx.x * 64;

    // ---------- phase 1: aggregate the block's 64 rows into LDS ----------
    {
        int g = l >> 3;            // sub-node in wave (0..7)
        int sl = l & 7;            // 16B feature slice (0..7)
        int nl = w * 8 + g;        // node_local (0..63)
        int i = r0 + nl;
        int ii = min(i, n - 1);
        int2 bd = re[ii];
        int e0 = bd.x;
        int cnt = (i < n) ? (bd.y - bd.x) : 0;
        int pc4 = (cnt + 3) & ~3;  // pad-4 (<= stored pad-8 region, ZOFF fill)
        const char* base = (const char*)hb + sl * 16;

        vf2 A[4], B[4];
#pragma unroll
        for (int f = 0; f < 4; f++) { A[f] = (vf2){0.f, 0.f}; B[f] = (vf2){0.f, 0.f}; }

        // e0 is a multiple of 8 -> soff + e0 + it is 16B-aligned
        for (int it = 0; it < pc4; it += 4) {
            vu4 ov = *(const vu4*)(soff + e0 + it);
            uint4 d0 = *(const uint4*)(base + ov.x);
            uint4 d1 = *(const uint4*)(base + ov.y);
            uint4 d2 = *(const uint4*)(base + ov.z);
            uint4 d3 = *(const uint4*)(base + ov.w);
            A[0] += bpair(d0.x); A[1] += bpair(d0.y);
            A[2] += bpair(d0.z); A[3] += bpair(d0.w);
            B[0] += bpair(d1.x); B[1] += bpair(d1.y);
            B[2] += bpair(d1.z); B[3] += bpair(d1.w);
            A[0] += bpair(d2.x); A[1] += bpair(d2.y);
            A[2] += bpair(d2.z); A[3] += bpair(d2.w);
            B[0] += bpair(d3.x); B[1] += bpair(d3.y);
            B[2] += bpair(d3.z); B[3] += bpair(d3.w);
        }

        vf2 s0 = A[0] + B[0];
        vf2 s1 = A[1] + B[1];
        vf2 s2 = A[2] + B[2];
        vf2 s3 = A[3] + B[3];
        uint4 o;
        o.x = pk2(s0.x, s0.y);
        o.y = pk2(s1.x, s1.y);
        o.z = pk2(s2.x, s2.y);
        o.w = pk2(s3.x, s3.y);
        int c16 = sl ^ (nl & 7);   // XOR swizzle of 16B chunks within the row
        *(uint4*)&agg_lds[nl][c16 * 4] = o;
    }
    __syncthreads();

    // ---------- phase 2: MFMA gemm (waves 0-3) ----------
    if (w < 4) {
        int lm = l & 15, q = l >> 4;
        int row = w * 16 + lm;
        int arow = r0 + row;
        if (arow >= n) arow = n - 1;
        const unsigned short* ah = hb + (size_t)arow * 64 + q * 8;
        vbf8 afr[4];
        afr[0] = *(const vbf8*)(ah);
        afr[1] = *(const vbf8*)(ah + 32);
        afr[2] = *(const vbf8*)&agg_lds[row][((q) ^ (lm & 7)) * 4];
        afr[3] = *(const vbf8*)&agg_lds[row][((q + 4) ^ (lm & 7)) * 4];

        vf4 acc[4];
#pragma unroll
        for (int t = 0; t < 4; t++) acc[t] = (vf4){0.f, 0.f, 0.f, 0.f};

#pragma unroll
        for (int t = 0; t < 4; t++) {
            const unsigned short* wrow = wt + (size_t)(t * 16 + lm) * 128 + q * 8;
#pragma unroll
            for (int s = 0; s < 4; s++) {
                vbf8 bfr = *(const vbf8*)(wrow + s * 32);
                acc[t] = __builtin_amdgcn_mfma_f32_16x16x32_bf16(afr[s], bfr, acc[t], 0, 0, 0);
            }
        }

        float* sw_ = scx[w];
#pragma unroll
        for (int t = 0; t < 4; t++) {
            float b = brel[t * 16 + lm];
#pragma unroll
            for (int i = 0; i < 4; i++) {
                float v = acc[t][i] + b;
                if (RELU) v = fmaxf(v, 0.f);
                sw_[(q * 4 + i) * 68 + t * 16 + lm] = v;
            }
        }
        int rr = l >> 2, cs = l & 3;
        int node = r0 + w * 16 + rr;
        if (node < n) {
            const float* rp = sw_ + rr * 68 + cs * 16;
            float4 v0 = *(const float4*)(rp);
            float4 v1 = *(const float4*)(rp + 4);
            float4 v2 = *(const float4*)(rp + 8);
            float4 v3 = *(const float4*)(rp + 12);
            vu4 o0, o1;
            o0.x = pk2(v0.x, v0.y);
            o0.y = pk2(v0.z, v0.w);
            o0.z = pk2(v1.x, v1.y);
            o0.w = pk2(v1.z, v1.w);
            o1.x = pk2(v2.x, v2.y);
            o1.y = pk2(v2.z, v2.w);
            o1.z = pk2(v3.x, v3.y);
            o1.w = pk2(v3.z, v3.w);
            vu4* op = (vu4*)(hbout + (size_t)node * 64 + cs * 16);
            op[0] = o0;
            op[1] = o1;
        }
    }
}

// ---------------- fused pool + MLP head (one block per graph) --------------
// r9: pooling vectorized — uint loads (2 bf16/thread), 8-way node-parallel
// (lane = feature-pair l2 0..31, c = node-group 0..7), 4-deep unroll.
// 2x fewer load instructions + 2x node parallelism vs scalar 2B loads.

__global__ __launch_bounds__(256) void k_poolmlp(
    const unsigned short* __restrict__ hb, const int* __restrict__ batch,
    const float* __restrict__ T, const float* __restrict__ w1,
    const float* __restrict__ b1, const float* __restrict__ w2,
    const float* __restrict__ b2, const float* __restrict__ w3,
    const float* __restrict__ b3, float* __restrict__ out, int n) {
    __shared__ float psum[8][64];
    __shared__ float pmax[8][64];
    __shared__ float sin_[200];
    __shared__ float so1[256];
    __shared__ float red[256];
    int g = blockIdx.x, t = threadIdx.x;
    int l2 = t & 31, c = t >> 5;   // feature-pair (0..31), node-group (0..7)

    // bounds via binary search (batch sorted)
    int lo = 0, hi = n;
    while (lo < hi) { int m = (lo + hi) >> 1; if (batch[m] < g) lo = m + 1; else hi = m; }
    int s0 = lo;
    int lo2 = s0, hi2 = n;
    while (lo2 < hi2) { int m = (lo2 + hi2) >> 1; if (batch[m] < g + 1) lo2 = m + 1; else hi2 = m; }
    int s1 = lo2;

    // pooling: uint (bf16x2) loads, unroll x4 (independent loads in flight)
    const unsigned int* hbu = (const unsigned int*)hb;   // 32 uints per row
    vf2 sa0 = (vf2){0.f, 0.f}, sa1 = sa0, sa2 = sa0, sa3 = sa0;
    vf2 ma0 = (vf2){-INFINITY, -INFINITY}, ma1 = ma0, ma2 = ma0, ma3 = ma0;
    int nn = s0 + c;
    for (; nn + 24 < s1; nn += 32) {
        unsigned d0 = hbu[(size_t)nn * 32 + l2];
        unsigned d1 = hbu[(size_t)(nn + 8) * 32 + l2];
        unsigned d2 = hbu[(size_t)(nn + 16) * 32 + l2];
        unsigned d3 = hbu[(size_t)(nn + 24) * 32 + l2];
        vf2 p0 = bpair(d0), p1 = bpair(d1), p2 = bpair(d2), p3 = bpair(d3);
        sa0 += p0; sa1 += p1; sa2 += p2; sa3 += p3;
        ma0.x = fmaxf(ma0.x, p0.x); ma0.y = fmaxf(ma0.y, p0.y);
        ma1.x = fmaxf(ma1.x, p1.x); ma1.y = fmaxf(ma1.y, p1.y);
        ma2.x = fmaxf(ma2.x, p2.x); ma2.y = fmaxf(ma2.y, p2.y);
        ma3.x = fmaxf(ma3.x, p3.x); ma3.y = fmaxf(ma3.y, p3.y);
    }
    for (; nn < s1; nn += 8) {
        unsigned d = hbu[(size_t)nn * 32 + l2];
        vf2 p = bpair(d);
        sa0 += p;
        ma0.x = fmaxf(ma0.x, p.x); ma0.y = fmaxf(ma0.y, p.y);
    }
    vf2 sv = (sa0 + sa1) + (sa2 + sa3);
    float mvx = fmaxf(fmaxf(ma0.x, ma1.x), fmaxf(ma2.x, ma3.x));
    float mvy = fmaxf(fmaxf(ma0.y, ma1.y), fmaxf(ma2.y, ma3.y));
    psum[c][2 * l2] = sv.x;
    psum[c][2 * l2 + 1] = sv.y;
    pmax[c][2 * l2] = mvx;
    pmax[c][2 * l2 + 1] = mvy;
    __syncthreads();
    if (t < 64) {
        float s = 0.f;
        float mx = -INFINITY;
#pragma unroll
        for (int cc = 0; cc < 8; cc++) {
            s += psum[cc][t];
            mx = fmaxf(mx, pmax[cc][t]);
        }
        int cnt = s1 - s0;
        float mean = s / fmaxf((float)cnt, 1.f);
        if (cnt == 0) mx = 0.f;
        sin_[t] = mx;
        sin_[64 + t] = mean;
        sin_[128 + t] = s;
        if (t == 0) {
            sin_[192] = T[g];
#pragma unroll
            for (int z = 193; z < 200; z++) sin_[z] = 0.f;  // pad for x8 batch
        }
    }
    __syncthreads();

    // layer 1: 193-K matvec, batched x8 (pad zeros make 200 safe)
    float a = b1[t];
    {
        float wv[8];
        for (int k = 0; k < 192; k += 8) {
#pragma unroll
            for (int u = 0; u < 8; u++) wv[u] = w1[(k + u) * 256 + t];
#pragma unroll
            for (int u = 0; u < 8; u++) a += sin_[k + u] * wv[u];
        }
        a += sin_[192] * w1[192 * 256 + t];
    }
    a = fmaxf(a, 0.f);
    so1[t] = a;
    __syncthreads();

    // layer 2: 256-K matvec, batched x8
    float a2 = b2[t];
    {
        float wv[8];
        for (int k = 0; k < 256; k += 8) {
#pragma unroll
            for (int u = 0; u < 8; u++) wv[u] = w2[(k + u) * 256 + t];
#pragma unroll
            for (int u = 0; u < 8; u++) a2 += so1[k + u] * wv[u];
        }
    }
    a2 = fmaxf(a2, 0.f);
    red[t] = a2 * w3[t];
    __syncthreads();
    for (int s = 128; s > 0; s >>= 1) {
        if (t < s) red[t] += red[t + s];
        __syncthreads();
    }
    if (t == 0) out[g] = red[0] + b3[0];
}

extern "C" void kernel_launch(void* const* d_in, const int* in_sizes, int n_in,
                              void* d_out, int out_size, void* d_ws, size_t ws_size,
                              hipStream_t stream) {
    const int N = N_NODES, E = N_EDGES, G = N_GRAPHS;

    const float* x = (const float*)d_in[0];
    const int* ei = (const int*)d_in[1];
    const int* batch = (const int*)d_in[2];
    const float* T = (const float*)d_in[3];
    const float* wrel[4] = {(const float*)d_in[4], (const float*)d_in[7],
                            (const float*)d_in[10], (const float*)d_in[13]};
    const float* brel[4] = {(const float*)d_in[5], (const float*)d_in[8],
                            (const float*)d_in[11], (const float*)d_in[14]};
    const float* wroot[4] = {(const float*)d_in[6], (const float*)d_in[9],
                             (const float*)d_in[12], (const float*)d_in[15]};
    const float* w1 = (const float*)d_in[16];
    const float* b1 = (const float*)d_in[17];
    const float* w2 = (const float*)d_in[18];
    const float* b2 = (const float*)d_in[19];
    const float* w3 = (const float*)d_in[20];
    const float* b3 = (const float*)d_in[21];
    float* out = (float*)d_out;

    const int* esrc = ei;
    const int* edst = ei + E;

    // workspace layout (~47 MB)
    char* ws = (char*)d_ws;
    size_t off = 0;
    auto alloc = [&](size_t bytes) {
        size_t r = off;
        off = (off + bytes + 255) & ~(size_t)255;
        return r;
    };
    int* lofs = (int*)(ws + alloc((size_t)SCAT_BLOCKS * LOFS_W * 4));
    int2* re = (int2*)(ws + alloc((size_t)N * 8));
    unsigned int* soff = (unsigned int*)(ws + alloc((size_t)NB * CAP * 4));
    unsigned int* ebuf = (unsigned int*)(ws + alloc((size_t)SCAT_BLOCKS * EDGES_PER_BLOCK * 4));
    unsigned short* hbA = (unsigned short*)(ws + alloc((size_t)N * 64 * 2 + 128));
    unsigned short* hbB = (unsigned short*)(ws + alloc((size_t)N * 64 * 2 + 128));
    unsigned short* wt = (unsigned short*)(ws + alloc((size_t)4 * 64 * 128 * 2));

    // 1. prep: mega (LDS bucket-sort scatter + f2b + wprep), then fscatter2
    k_mega<<<SCAT_BLOCKS + F2B_BLOCKS + WPREP_BLOCKS, 256, 0, stream>>>(
        esrc, edst, lofs, ebuf, (const float4*)x, (uint2*)hbA,
        wroot[0], wrel[0], wroot[1], wrel[1],
        wroot[2], wrel[2], wroot[3], wrel[3], wt);
    k_fscatter2<<<NB, 256, 0, stream>>>(ebuf, lofs, re, soff, hbA, hbB, N);

    // 2. four fused conv layers (agg in LDS + MFMA gemm, bf16 ping-pong)
    k_layer<1><<<FUSE_BLOCKS, 512, 0, stream>>>(hbA, wt + 0 * 8192, brel[0], hbB, re, soff, N);
    k_layer<1><<<FUSE_BLOCKS, 512, 0, stream>>>(hbB, wt + 1 * 8192, brel[1], hbA, re, soff, N);
    k_layer<1><<<FUSE_BLOCKS, 512, 0, stream>>>(hbA, wt + 2 * 8192, brel[2], hbB, re, soff, N);
    k_layer<0><<<FUSE_BLOCKS, 512, 0, stream>>>(hbB, wt + 3 * 8192, brel[3], hbA, re, soff, N);

    // 3. fused pooling + MLP head
    k_poolmlp<<<G, 256, 0, stream>>>(hbA, batch, T, w1, b1, w2, b2, w3, b3, out, N);
}